// Round 17
// baseline (1521.675 us; speedup 1.0000x reference)
//
#include <hip/hip_runtime.h>
#include <hip/hip_bf16.h>
#include <stdint.h>

// ---------- types / helpers ----------
typedef short bf16x8 __attribute__((ext_vector_type(8)));
typedef float f32x4 __attribute__((ext_vector_type(4)));
typedef _Float16 half2v __attribute__((ext_vector_type(2)));

typedef const __attribute__((address_space(1))) unsigned int glob_u32;
typedef __attribute__((address_space(3))) unsigned int lds_u32;

__device__ __forceinline__ void gl_lds16(const void* g, void* s) {
  __builtin_amdgcn_global_load_lds((glob_u32*)g, (lds_u32*)s, 16, 0, 0);
}

__device__ __forceinline__ unsigned short f2bf(float f) {
  __hip_bfloat16 h = __float2bfloat16(f);
  return __builtin_bit_cast(unsigned short, h);
}
__device__ __forceinline__ float bf2f(unsigned short u) {
  __hip_bfloat16 h = __builtin_bit_cast(__hip_bfloat16, u);
  return __bfloat162float(h);
}

__device__ __forceinline__ float sigm_fast(float x) {
  float e = __expf(-x);
  return __builtin_amdgcn_rcpf(1.f + e);
}
__device__ __forceinline__ float tanh_fast(float x) {
  float e = __expf(2.f * x);                  // inf-safe: rcp(inf)=0 -> 1
  return 1.f - 2.f * __builtin_amdgcn_rcpf(e + 1.f);
}

// packed f16 dot: acc += a.x*b.x + a.y*b.y  (v_dot2_f32_f16, f32 accumulate)
__device__ __forceinline__ float dot2(unsigned a, unsigned b, float acc) {
  return __builtin_amdgcn_fdot2(__builtin_bit_cast(half2v, a),
                                __builtin_bit_cast(half2v, b), acc, false);
}

// ---------- split fp32 -> bf16 hi/lo ----------
__global__ void split_hl(const float* __restrict__ src,
                         unsigned short* __restrict__ hi,
                         unsigned short* __restrict__ lo, int n4) {
  int i = blockIdx.x * blockDim.x + threadIdx.x;
  if (i >= n4) return;
  float4 v = reinterpret_cast<const float4*>(src)[i];
  ushort4 h, l;
  h.x = f2bf(v.x); l.x = f2bf(v.x - bf2f(h.x));
  h.y = f2bf(v.y); l.y = f2bf(v.y - bf2f(h.y));
  h.z = f2bf(v.z); l.z = f2bf(v.z - bf2f(h.z));
  h.w = f2bf(v.w); l.w = f2bf(v.w - bf2f(h.w));
  reinterpret_cast<ushort4*>(hi)[i] = h;
  reinterpret_cast<ushort4*>(lo)[i] = l;
}

// ---------- split fp32 -> bf16 hi only (decoder weights) ----------
__global__ void split_h(const float* __restrict__ src,
                        unsigned short* __restrict__ hi, int n4) {
  int i = blockIdx.x * blockDim.x + threadIdx.x;
  if (i >= n4) return;
  float4 v = reinterpret_cast<const float4*>(src)[i];
  ushort4 h;
  h.x = f2bf(v.x); h.y = f2bf(v.y); h.z = f2bf(v.z); h.w = f2bf(v.w);
  reinterpret_cast<ushort4*>(hi)[i] = h;
}

// ---------- embedding gather + split ----------
__global__ void gather_split(const int* __restrict__ x, const float* __restrict__ emb,
                             unsigned short* __restrict__ hi,
                             unsigned short* __restrict__ lo) {
  int i = blockIdx.x * 256 + threadIdx.x;  // [0, 4096*128)
  int m = i >> 7, k4 = i & 127;
  long row = x[m];
  float4 v = reinterpret_cast<const float4*>(emb + row * 512)[k4];
  ushort4 h, l;
  h.x = f2bf(v.x); l.x = f2bf(v.x - bf2f(h.x));
  h.y = f2bf(v.y); l.y = f2bf(v.y - bf2f(h.y));
  h.z = f2bf(v.z); l.z = f2bf(v.z - bf2f(h.z));
  h.w = f2bf(v.w); l.w = f2bf(v.w - bf2f(h.w));
  reinterpret_cast<ushort4*>(hi)[m * 128 + k4] = h;
  reinterpret_cast<ushort4*>(lo)[m * 128 + k4] = l;
}

// ---------- split-bf16 GEMM (3-product, for xproj): C = A@B^T + bias ----------
__global__ __launch_bounds__(256) void gemm_split(
    const unsigned short* __restrict__ Ahi, const unsigned short* __restrict__ Alo,
    const unsigned short* __restrict__ Bhi, const unsigned short* __restrict__ Blo,
    float* __restrict__ C, const float* __restrict__ bias1,
    const float* __restrict__ bias2, int N, int mtiles) {
  __shared__ unsigned short lds[4][128 * 64];
  int nwg = gridDim.x;
  int wid = (blockIdx.x & 7) * (nwg >> 3) + (blockIdx.x >> 3);
  int mt = wid % mtiles, nt = wid / mtiles;
  int m0 = mt * 128, n0 = nt * 128;
  int tid = threadIdx.x, l = tid & 63, w = tid >> 6;
  int wm = (w & 1) * 64, wn = (w >> 1) * 64;

  f32x4 acc[4][4];
#pragma unroll
  for (int a = 0; a < 4; ++a)
#pragma unroll
    for (int b = 0; b < 4; ++b) acc[a][b] = f32x4{0.f, 0.f, 0.f, 0.f};

  const unsigned short* srcs[4] = {Ahi, Alo, Bhi, Blo};

  for (int kc = 0; kc < 8; ++kc) {
    __syncthreads();
#pragma unroll
    for (int tile = 0; tile < 4; ++tile) {
      const unsigned short* src = srcs[tile];
      int rbase = (tile < 2) ? m0 : n0;
#pragma unroll
      for (int i = 0; i < 4; ++i) {
        int G = (i * 4 + w) * 64 + l;
        int r = G >> 3, g = G & 7;
        int row = rbase + r;
        long gb = (long)row * 1024 + kc * 128 + ((g * 16) ^ ((r & 7) << 4));
        gl_lds16((const char*)src + gb, (char*)(&lds[tile][0]) + (i * 4 + w) * 1024);
      }
    }
    __syncthreads();

    const char* ldsb = (const char*)&lds[0][0];
#pragma unroll
    for (int ks = 0; ks < 2; ++ks) {
      bf16x8 ah[4], al[4], bh[4], bl[4];
      int biw = ks * 64 + ((l >> 4) * 16);
#pragma unroll
      for (int fm = 0; fm < 4; ++fm) {
        int row = wm + fm * 16 + (l & 15);
        int off = row * 128 + (biw ^ ((row & 7) << 4));
        ah[fm] = *reinterpret_cast<const bf16x8*>(ldsb + off);
        al[fm] = *reinterpret_cast<const bf16x8*>(ldsb + 16384 + off);
      }
#pragma unroll
      for (int fn = 0; fn < 4; ++fn) {
        int row = wn + fn * 16 + (l & 15);
        int off = row * 128 + (biw ^ ((row & 7) << 4));
        bh[fn] = *reinterpret_cast<const bf16x8*>(ldsb + 32768 + off);
        bl[fn] = *reinterpret_cast<const bf16x8*>(ldsb + 49152 + off);
      }
#pragma unroll
      for (int fm = 0; fm < 4; ++fm)
#pragma unroll
        for (int fn = 0; fn < 4; ++fn) {
          acc[fm][fn] = __builtin_amdgcn_mfma_f32_16x16x32_bf16(ah[fm], bh[fn], acc[fm][fn], 0, 0, 0);
          acc[fm][fn] = __builtin_amdgcn_mfma_f32_16x16x32_bf16(ah[fm], bl[fn], acc[fm][fn], 0, 0, 0);
          acc[fm][fn] = __builtin_amdgcn_mfma_f32_16x16x32_bf16(al[fm], bh[fn], acc[fm][fn], 0, 0, 0);
        }
    }
  }

#pragma unroll
  for (int fn = 0; fn < 4; ++fn) {
    int n = n0 + wn + fn * 16 + (l & 15);
    float bs = bias1[n];
    if (bias2) bs += bias2[n];
#pragma unroll
    for (int fm = 0; fm < 4; ++fm) {
      int mb = m0 + wm + fm * 16 + (l >> 4) * 4;
#pragma unroll
      for (int j = 0; j < 4; ++j)
        C[(long)(mb + j) * N + n] = acc[fm][fn][j] + bs;
    }
  }
}

// ---------- plain bf16 GEMM 128x128 (single product, decoder) ----------
// R12-proven 8x1 XCD map: each XCD owns 4 fixed m-tiles (A slice L2-resident).
__global__ __launch_bounds__(256) void gemm_plain(
    const unsigned short* __restrict__ Ahi, const unsigned short* __restrict__ Bhi,
    float* __restrict__ C, const float* __restrict__ bias1, int N) {
  __shared__ unsigned short lds[2][128 * 64];
  int xcd = blockIdx.x & 7;
  int wid = blockIdx.x >> 3;
  int mt = xcd * 4 + (wid & 3);
  int nt = wid >> 2;
  int m0 = mt * 128, n0 = nt * 128;
  int tid = threadIdx.x, l = tid & 63, w = tid >> 6;
  int wm = (w & 1) * 64, wn = (w >> 1) * 64;

  f32x4 acc[4][4];
#pragma unroll
  for (int a = 0; a < 4; ++a)
#pragma unroll
    for (int b = 0; b < 4; ++b) acc[a][b] = f32x4{0.f, 0.f, 0.f, 0.f};

  const unsigned short* srcs[2] = {Ahi, Bhi};

  for (int kc = 0; kc < 8; ++kc) {
    __syncthreads();
#pragma unroll
    for (int tile = 0; tile < 2; ++tile) {
      const unsigned short* src = srcs[tile];
      int rbase = (tile < 1) ? m0 : n0;
#pragma unroll
      for (int i = 0; i < 4; ++i) {
        int G = (i * 4 + w) * 64 + l;
        int r = G >> 3, g = G & 7;
        int row = rbase + r;
        if (tile == 1 && row >= N) row = n0;
        long gb = (long)row * 1024 + kc * 128 + ((g * 16) ^ ((r & 7) << 4));
        gl_lds16((const char*)src + gb, (char*)(&lds[tile][0]) + (i * 4 + w) * 1024);
      }
    }
    __syncthreads();

    const char* ldsb = (const char*)&lds[0][0];
#pragma unroll
    for (int ks = 0; ks < 2; ++ks) {
      bf16x8 ah[4], bh[4];
      int biw = ks * 64 + ((l >> 4) * 16);
#pragma unroll
      for (int fm = 0; fm < 4; ++fm) {
        int row = wm + fm * 16 + (l & 15);
        int off = row * 128 + (biw ^ ((row & 7) << 4));
        ah[fm] = *reinterpret_cast<const bf16x8*>(ldsb + off);
      }
#pragma unroll
      for (int fn = 0; fn < 4; ++fn) {
        int row = wn + fn * 16 + (l & 15);
        int off = row * 128 + (biw ^ ((row & 7) << 4));
        bh[fn] = *reinterpret_cast<const bf16x8*>(ldsb + 16384 + off);
      }
#pragma unroll
      for (int fm = 0; fm < 4; ++fm)
#pragma unroll
        for (int fn = 0; fn < 4; ++fn)
          acc[fm][fn] = __builtin_amdgcn_mfma_f32_16x16x32_bf16(ah[fm], bh[fn], acc[fm][fn], 0, 0, 0);
    }
  }

#pragma unroll
  for (int fn = 0; fn < 4; ++fn) {
    int n = n0 + wn + fn * 16 + (l & 15);
    if (n < N) {
      float bs = bias1[n];
#pragma unroll
      for (int fm = 0; fm < 4; ++fm) {
        int mb = m0 + wm + fm * 16 + (l >> 4) * 4;
#pragma unroll
        for (int j = 0; j < 4; ++j)
          C[(long)(mb + j) * N + n] = acc[fm][fn][j] + bs;
      }
    }
  }
}

// ---------- persistent LSTM: R12 structure, poll deepened 2->4 ----------
// 256 blocks x 256 threads; batch = bid&7, slice = bid>>3.
// f32 u64 4-deep sentinel poll (period ~RT/4); weights f16x2-packed
// (64 VGPRs, no remat); dot = 16 ds_read_b128 + 64 v_dot2_f32_f16.
__global__ __launch_bounds__(256, 1) void lstm_persistent(
    const float* __restrict__ xproj,   // [8][512][2048] (biases folded in)
    const float* __restrict__ whh,     // [2048][512]
    float* lstm_f32,                   // [8][512][512] sentinel-initialized
    unsigned short* __restrict__ lstm_hi) {
  int bid = blockIdx.x;
  int batch = bid & 7, slice = bid >> 3;
  int tid = threadIdx.x, l = tid & 63, w = tid >> 6;
  int g = l >> 4, e = l & 15;
  long R = (long)g * 512 + slice * 16 + e;  // gate row in [0,2048)

  __shared__ unsigned hs_pk[256];      // h(t-1) as f16 pairs, 1 KiB
  __shared__ float part_s[2][4][64];   // double-buffered partials

  // ---- weights packed f16x2 along k: 64 u32/lane, pinned ----
  unsigned wpk[64];
  {
    const float2* wp = reinterpret_cast<const float2*>(whh + R * 512 + w * 128);
#pragma unroll
    for (int jj = 0; jj < 64; ++jj) {
      float2 v = wp[jj];
      wpk[jj] = __builtin_bit_cast(unsigned, __builtin_amdgcn_cvt_pkrtz(v.x, v.y));
    }
  }
#pragma unroll
  for (int jj = 0; jj < 64; jj += 4)
    asm volatile("" : "+v"(wpk[jj]), "+v"(wpk[jj + 1]), "+v"(wpk[jj + 2]), "+v"(wpk[jj + 3]));

  const float* xbase = xproj + (long)batch * 512 * 2048 + g * 512 + slice * 16 + e;
  float* hrow_base = lstm_f32 + (long)batch * 512 * 512;
  float c_reg = 0.f;

#define PL(p) __hip_atomic_load((p), __ATOMIC_RELAXED, __HIP_MEMORY_SCOPE_AGENT)
#define BAD(u) (((unsigned)(u)) == 0xFFFFFFFFu || ((unsigned)((u) >> 32)) == 0xFFFFFFFFu)

  for (int t = 0; t < 512; ++t) {
    float xp = 0.f;
    if (w == 0) xp = xbase[(long)t * 2048];

    float a0 = 0.f, a1 = 0.f, a2 = 0.f, a3 = 0.f;
    if (t > 0) {
      // 4-deep pipelined sentinel poll: lane polls h[w*128+2l, +1] (8B)
      const unsigned long long* src = reinterpret_cast<const unsigned long long*>(
          hrow_base + (long)(t - 1) * 512 + w * 128) + l;
      unsigned long long p0 = PL(src), p1 = PL(src), p2 = PL(src), p3 = PL(src);
      while (BAD(p0)) { p0 = p1; p1 = p2; p2 = p3; p3 = PL(src); }
      float hx = __builtin_bit_cast(float, (unsigned)p0);
      float hy = __builtin_bit_cast(float, (unsigned)(p0 >> 32));
      hs_pk[w * 64 + l] =
          __builtin_bit_cast(unsigned, __builtin_amdgcn_cvt_pkrtz(hx, hy));
      asm volatile("s_waitcnt lgkmcnt(0)" ::: "memory");
      __builtin_amdgcn_sched_barrier(0);
      // dot: 16 x b128 LDS reads (wave-uniform broadcast) + 64 fdot2
      const uint4* hv = reinterpret_cast<const uint4*>(&hs_pk[w * 64]);
#pragma unroll
      for (int jj = 0; jj < 16; ++jj) {
        uint4 q = hv[jj];
        a0 = dot2(wpk[jj * 4 + 0], q.x, a0);
        a1 = dot2(wpk[jj * 4 + 1], q.y, a1);
        a2 = dot2(wpk[jj * 4 + 2], q.z, a2);
        a3 = dot2(wpk[jj * 4 + 3], q.w, a3);
      }
    }
    part_s[t & 1][w][l] = (a0 + a1) + (a2 + a3);
    __syncthreads();

    if (w == 0) {
      float sum = xp + part_s[t & 1][0][l] + part_s[t & 1][1][l] +
                  part_s[t & 1][2][l] + part_s[t & 1][3][l];
      float val = (g == 2) ? tanh_fast(sum) : sigm_fast(sum);
      float vf = __shfl(val, e + 16);   // f gate
      float vg = __shfl(val, e + 32);   // g gate
      float vo = __shfl(val, e + 48);   // o gate
      if (l < 16) {
        float c = vf * c_reg + val * vg;   // val = i for lanes 0..15
        c_reg = c;
        float h = vo * tanh_fast(c);
        long oidx = ((long)batch * 512 + t) * 512 + slice * 16 + l;
        __hip_atomic_store(reinterpret_cast<unsigned int*>(lstm_f32) + oidx,
                           __builtin_bit_cast(unsigned int, h),
                           __ATOMIC_RELAXED, __HIP_MEMORY_SCOPE_AGENT);
        lstm_hi[oidx] = f2bf(h);
      }
    }
    // no trailing barrier: part_s double-buffered; hs_pk segment wave-private
  }
#undef PL
#undef BAD
}

// ---------- launch ----------
extern "C" void kernel_launch(void* const* d_in, const int* in_sizes, int n_in,
                              void* d_out, int out_size, void* d_ws, size_t ws_size,
                              hipStream_t stream) {
  const int*   x         = (const int*)d_in[0];
  const float* embedding = (const float*)d_in[2];
  const float* w_ih      = (const float*)d_in[3];
  const float* w_hh      = (const float*)d_in[4];
  const float* b_ih      = (const float*)d_in[5];
  const float* b_hh      = (const float*)d_in[6];
  const float* dec_w     = (const float*)d_in[7];
  const float* dec_b     = (const float*)d_in[8];

  char* ws = (char*)d_ws;
  float* xproj = (float*)ws;                      ws += (size_t)4096 * 2048 * 4;
  float* lstmf = (float*)ws;                      ws += (size_t)4096 * 512 * 4;
  unsigned short* lstm_hi = (unsigned short*)ws;  ws += (size_t)4096 * 512 * 2;
  unsigned short* emb_hi  = (unsigned short*)ws;  ws += (size_t)4096 * 512 * 2;
  unsigned short* emb_lo  = (unsigned short*)ws;  ws += (size_t)4096 * 512 * 2;
  unsigned short* wih_hi  = (unsigned short*)ws;  ws += (size_t)2048 * 512 * 2;
  unsigned short* wih_lo  = (unsigned short*)ws;  ws += (size_t)2048 * 512 * 2;
  unsigned short* dw_hi   = (unsigned short*)ws;  ws += (size_t)50000 * 512 * 2;

  // reset h sentinel (poll buffer) every call — determinism across replays
  hipMemsetAsync(lstmf, 0xFF, (size_t)4096 * 512 * 4, stream);

  split_hl<<<1024, 256, 0, stream>>>(w_ih, wih_hi, wih_lo, 2048 * 512 / 4);
  split_h<<<25000, 256, 0, stream>>>(dec_w, dw_hi, 50000 * 512 / 4);
  gather_split<<<2048, 256, 0, stream>>>(x, embedding, emb_hi, emb_lo);

  // xproj = embed @ w_ih^T + (b_ih + b_hh)   [3-product: feeds the recurrence]
  gemm_split<<<32 * 16, 256, 0, stream>>>(emb_hi, emb_lo, wih_hi, wih_lo, xproj,
                                          b_ih, b_hh, 2048, 32);

  {
    void* args[] = {(void*)&xproj, (void*)&w_hh, (void*)&lstmf, (void*)&lstm_hi};
    hipLaunchCooperativeKernel((void*)lstm_persistent, dim3(256), dim3(256), args, 0, stream);
  }

  // y = lstm_out @ dec_w^T + dec_b   [single bf16 product, 128^2 tile, 8x1 XCD map]
  gemm_plain<<<32 * 391, 256, 0, stream>>>(lstm_hi, dw_hi, (float*)d_out, dec_b, 50000);
}

// Round 18
// 1220.633 us; speedup vs baseline: 1.2466x; 1.2466x over previous
//
#include <hip/hip_runtime.h>
#include <hip/hip_bf16.h>
#include <stdint.h>

// ---------- types / helpers ----------
typedef short bf16x8 __attribute__((ext_vector_type(8)));
typedef float f32x4 __attribute__((ext_vector_type(4)));
typedef _Float16 half2v __attribute__((ext_vector_type(2)));

typedef const __attribute__((address_space(1))) unsigned int glob_u32;
typedef __attribute__((address_space(3))) unsigned int lds_u32;

__device__ __forceinline__ void gl_lds16(const void* g, void* s) {
  __builtin_amdgcn_global_load_lds((glob_u32*)g, (lds_u32*)s, 16, 0, 0);
}

__device__ __forceinline__ unsigned short f2bf(float f) {
  __hip_bfloat16 h = __float2bfloat16(f);
  return __builtin_bit_cast(unsigned short, h);
}
__device__ __forceinline__ float bf2f(unsigned short u) {
  __hip_bfloat16 h = __builtin_bit_cast(__hip_bfloat16, u);
  return __bfloat162float(h);
}

__device__ __forceinline__ float sigm_fast(float x) {
  float e = __expf(-x);
  return __builtin_amdgcn_rcpf(1.f + e);
}
__device__ __forceinline__ float tanh_fast(float x) {
  float e = __expf(2.f * x);                  // inf-safe: rcp(inf)=0 -> 1
  return 1.f - 2.f * __builtin_amdgcn_rcpf(e + 1.f);
}

// packed f16 dot: acc += a.x*b.x + a.y*b.y  (v_dot2_f32_f16, f32 accumulate)
__device__ __forceinline__ float dot2(unsigned a, unsigned b, float acc) {
  return __builtin_amdgcn_fdot2(__builtin_bit_cast(half2v, a),
                                __builtin_bit_cast(half2v, b), acc, false);
}

// ---------- split fp32 -> bf16 hi/lo ----------
__global__ void split_hl(const float* __restrict__ src,
                         unsigned short* __restrict__ hi,
                         unsigned short* __restrict__ lo, int n4) {
  int i = blockIdx.x * blockDim.x + threadIdx.x;
  if (i >= n4) return;
  float4 v = reinterpret_cast<const float4*>(src)[i];
  ushort4 h, l;
  h.x = f2bf(v.x); l.x = f2bf(v.x - bf2f(h.x));
  h.y = f2bf(v.y); l.y = f2bf(v.y - bf2f(h.y));
  h.z = f2bf(v.z); l.z = f2bf(v.z - bf2f(h.z));
  h.w = f2bf(v.w); l.w = f2bf(v.w - bf2f(h.w));
  reinterpret_cast<ushort4*>(hi)[i] = h;
  reinterpret_cast<ushort4*>(lo)[i] = l;
}

// ---------- split fp32 -> bf16 hi only (decoder weights) ----------
__global__ void split_h(const float* __restrict__ src,
                        unsigned short* __restrict__ hi, int n4) {
  int i = blockIdx.x * blockDim.x + threadIdx.x;
  if (i >= n4) return;
  float4 v = reinterpret_cast<const float4*>(src)[i];
  ushort4 h;
  h.x = f2bf(v.x); h.y = f2bf(v.y); h.z = f2bf(v.z); h.w = f2bf(v.w);
  reinterpret_cast<ushort4*>(hi)[i] = h;
}

// ---------- embedding gather + split ----------
__global__ void gather_split(const int* __restrict__ x, const float* __restrict__ emb,
                             unsigned short* __restrict__ hi,
                             unsigned short* __restrict__ lo) {
  int i = blockIdx.x * 256 + threadIdx.x;  // [0, 4096*128)
  int m = i >> 7, k4 = i & 127;
  long row = x[m];
  float4 v = reinterpret_cast<const float4*>(emb + row * 512)[k4];
  ushort4 h, l;
  h.x = f2bf(v.x); l.x = f2bf(v.x - bf2f(h.x));
  h.y = f2bf(v.y); l.y = f2bf(v.y - bf2f(h.y));
  h.z = f2bf(v.z); l.z = f2bf(v.z - bf2f(h.z));
  h.w = f2bf(v.w); l.w = f2bf(v.w - bf2f(h.w));
  reinterpret_cast<ushort4*>(hi)[m * 128 + k4] = h;
  reinterpret_cast<ushort4*>(lo)[m * 128 + k4] = l;
}

// ---------- split-bf16 GEMM (3-product, for xproj): C = A@B^T + bias ----------
__global__ __launch_bounds__(256) void gemm_split(
    const unsigned short* __restrict__ Ahi, const unsigned short* __restrict__ Alo,
    const unsigned short* __restrict__ Bhi, const unsigned short* __restrict__ Blo,
    float* __restrict__ C, const float* __restrict__ bias1,
    const float* __restrict__ bias2, int N, int mtiles) {
  __shared__ unsigned short lds[4][128 * 64];
  int nwg = gridDim.x;
  int wid = (blockIdx.x & 7) * (nwg >> 3) + (blockIdx.x >> 3);
  int mt = wid % mtiles, nt = wid / mtiles;
  int m0 = mt * 128, n0 = nt * 128;
  int tid = threadIdx.x, l = tid & 63, w = tid >> 6;
  int wm = (w & 1) * 64, wn = (w >> 1) * 64;

  f32x4 acc[4][4];
#pragma unroll
  for (int a = 0; a < 4; ++a)
#pragma unroll
    for (int b = 0; b < 4; ++b) acc[a][b] = f32x4{0.f, 0.f, 0.f, 0.f};

  const unsigned short* srcs[4] = {Ahi, Alo, Bhi, Blo};

  for (int kc = 0; kc < 8; ++kc) {
    __syncthreads();
#pragma unroll
    for (int tile = 0; tile < 4; ++tile) {
      const unsigned short* src = srcs[tile];
      int rbase = (tile < 2) ? m0 : n0;
#pragma unroll
      for (int i = 0; i < 4; ++i) {
        int G = (i * 4 + w) * 64 + l;
        int r = G >> 3, g = G & 7;
        int row = rbase + r;
        long gb = (long)row * 1024 + kc * 128 + ((g * 16) ^ ((r & 7) << 4));
        gl_lds16((const char*)src + gb, (char*)(&lds[tile][0]) + (i * 4 + w) * 1024);
      }
    }
    __syncthreads();

    const char* ldsb = (const char*)&lds[0][0];
#pragma unroll
    for (int ks = 0; ks < 2; ++ks) {
      bf16x8 ah[4], al[4], bh[4], bl[4];
      int biw = ks * 64 + ((l >> 4) * 16);
#pragma unroll
      for (int fm = 0; fm < 4; ++fm) {
        int row = wm + fm * 16 + (l & 15);
        int off = row * 128 + (biw ^ ((row & 7) << 4));
        ah[fm] = *reinterpret_cast<const bf16x8*>(ldsb + off);
        al[fm] = *reinterpret_cast<const bf16x8*>(ldsb + 16384 + off);
      }
#pragma unroll
      for (int fn = 0; fn < 4; ++fn) {
        int row = wn + fn * 16 + (l & 15);
        int off = row * 128 + (biw ^ ((row & 7) << 4));
        bh[fn] = *reinterpret_cast<const bf16x8*>(ldsb + 32768 + off);
        bl[fn] = *reinterpret_cast<const bf16x8*>(ldsb + 49152 + off);
      }
#pragma unroll
      for (int fm = 0; fm < 4; ++fm)
#pragma unroll
        for (int fn = 0; fn < 4; ++fn) {
          acc[fm][fn] = __builtin_amdgcn_mfma_f32_16x16x32_bf16(ah[fm], bh[fn], acc[fm][fn], 0, 0, 0);
          acc[fm][fn] = __builtin_amdgcn_mfma_f32_16x16x32_bf16(ah[fm], bl[fn], acc[fm][fn], 0, 0, 0);
          acc[fm][fn] = __builtin_amdgcn_mfma_f32_16x16x32_bf16(al[fm], bh[fn], acc[fm][fn], 0, 0, 0);
        }
    }
  }

#pragma unroll
  for (int fn = 0; fn < 4; ++fn) {
    int n = n0 + wn + fn * 16 + (l & 15);
    float bs = bias1[n];
    if (bias2) bs += bias2[n];
#pragma unroll
    for (int fm = 0; fm < 4; ++fm) {
      int mb = m0 + wm + fm * 16 + (l >> 4) * 4;
#pragma unroll
      for (int j = 0; j < 4; ++j)
        C[(long)(mb + j) * N + n] = acc[fm][fn][j] + bs;
    }
  }
}

// ---------- plain bf16 GEMM 128x128 (single product, decoder) ----------
// 8x1 XCD map: each XCD owns 4 fixed m-tiles (A slice 524KB, L2-resident).
__global__ __launch_bounds__(256) void gemm_plain(
    const unsigned short* __restrict__ Ahi, const unsigned short* __restrict__ Bhi,
    float* __restrict__ C, const float* __restrict__ bias1, int N) {
  __shared__ unsigned short lds[2][128 * 64];
  int xcd = blockIdx.x & 7;
  int wid = blockIdx.x >> 3;
  int mt = xcd * 4 + (wid & 3);
  int nt = wid >> 2;
  int m0 = mt * 128, n0 = nt * 128;
  int tid = threadIdx.x, l = tid & 63, w = tid >> 6;
  int wm = (w & 1) * 64, wn = (w >> 1) * 64;

  f32x4 acc[4][4];
#pragma unroll
  for (int a = 0; a < 4; ++a)
#pragma unroll
    for (int b = 0; b < 4; ++b) acc[a][b] = f32x4{0.f, 0.f, 0.f, 0.f};

  const unsigned short* srcs[2] = {Ahi, Bhi};

  for (int kc = 0; kc < 8; ++kc) {
    __syncthreads();
#pragma unroll
    for (int tile = 0; tile < 2; ++tile) {
      const unsigned short* src = srcs[tile];
      int rbase = (tile < 1) ? m0 : n0;
#pragma unroll
      for (int i = 0; i < 4; ++i) {
        int G = (i * 4 + w) * 64 + l;
        int r = G >> 3, g = G & 7;
        int row = rbase + r;
        if (tile == 1 && row >= N) row = n0;
        long gb = (long)row * 1024 + kc * 128 + ((g * 16) ^ ((r & 7) << 4));
        gl_lds16((const char*)src + gb, (char*)(&lds[tile][0]) + (i * 4 + w) * 1024);
      }
    }
    __syncthreads();

    const char* ldsb = (const char*)&lds[0][0];
#pragma unroll
    for (int ks = 0; ks < 2; ++ks) {
      bf16x8 ah[4], bh[4];
      int biw = ks * 64 + ((l >> 4) * 16);
#pragma unroll
      for (int fm = 0; fm < 4; ++fm) {
        int row = wm + fm * 16 + (l & 15);
        int off = row * 128 + (biw ^ ((row & 7) << 4));
        ah[fm] = *reinterpret_cast<const bf16x8*>(ldsb + off);
      }
#pragma unroll
      for (int fn = 0; fn < 4; ++fn) {
        int row = wn + fn * 16 + (l & 15);
        int off = row * 128 + (biw ^ ((row & 7) << 4));
        bh[fn] = *reinterpret_cast<const bf16x8*>(ldsb + 16384 + off);
      }
#pragma unroll
      for (int fm = 0; fm < 4; ++fm)
#pragma unroll
        for (int fn = 0; fn < 4; ++fn)
          acc[fm][fn] = __builtin_amdgcn_mfma_f32_16x16x32_bf16(ah[fm], bh[fn], acc[fm][fn], 0, 0, 0);
    }
  }

#pragma unroll
  for (int fn = 0; fn < 4; ++fn) {
    int n = n0 + wn + fn * 16 + (l & 15);
    if (n < N) {
      float bs = bias1[n];
#pragma unroll
      for (int fm = 0; fm < 4; ++fm) {
        int mb = m0 + wm + fm * 16 + (l >> 4) * 4;
#pragma unroll
        for (int j = 0; j < 4; ++j)
          C[(long)(mb + j) * N + n] = acc[fm][fn][j] + bs;
      }
    }
  }
}

// ---------- persistent LSTM: R12-exact (657 us, reproduced 3x) ----------
// 256 blocks x 256 threads; batch = bid&7, slice = bid>>3.
// f32 u64 2-deep sentinel poll; weights f16x2-packed (64 VGPRs, no remat);
// dot = 16 ds_read_b128 + 64 v_dot2_f32_f16.
__global__ __launch_bounds__(256, 1) void lstm_persistent(
    const float* __restrict__ xproj,   // [8][512][2048] (biases folded in)
    const float* __restrict__ whh,     // [2048][512]
    float* lstm_f32,                   // [8][512][512] sentinel-initialized
    unsigned short* __restrict__ lstm_hi) {
  int bid = blockIdx.x;
  int batch = bid & 7, slice = bid >> 3;
  int tid = threadIdx.x, l = tid & 63, w = tid >> 6;
  int g = l >> 4, e = l & 15;
  long R = (long)g * 512 + slice * 16 + e;  // gate row in [0,2048)

  __shared__ unsigned hs_pk[256];      // h(t-1) as f16 pairs, 1 KiB
  __shared__ float part_s[2][4][64];   // double-buffered partials

  // ---- weights packed f16x2 along k: 64 u32/lane, pinned ----
  unsigned wpk[64];
  {
    const float2* wp = reinterpret_cast<const float2*>(whh + R * 512 + w * 128);
#pragma unroll
    for (int jj = 0; jj < 64; ++jj) {
      float2 v = wp[jj];
      wpk[jj] = __builtin_bit_cast(unsigned, __builtin_amdgcn_cvt_pkrtz(v.x, v.y));
    }
  }
#pragma unroll
  for (int jj = 0; jj < 64; jj += 4)
    asm volatile("" : "+v"(wpk[jj]), "+v"(wpk[jj + 1]), "+v"(wpk[jj + 2]), "+v"(wpk[jj + 3]));

  const float* xbase = xproj + (long)batch * 512 * 2048 + g * 512 + slice * 16 + e;
  float* hrow_base = lstm_f32 + (long)batch * 512 * 512;
  float c_reg = 0.f;

  for (int t = 0; t < 512; ++t) {
    float xp = 0.f;
    if (w == 0) xp = xbase[(long)t * 2048];

    float a0 = 0.f, a1 = 0.f, a2 = 0.f, a3 = 0.f;
    if (t > 0) {
      // 2-deep pipelined sentinel poll: lane polls h[w*128+2l, +1] (8B)
      const unsigned long long* src = reinterpret_cast<const unsigned long long*>(
          hrow_base + (long)(t - 1) * 512 + w * 128) + l;
      unsigned long long u = __hip_atomic_load(src, __ATOMIC_RELAXED, __HIP_MEMORY_SCOPE_AGENT);
      unsigned long long u2 = __hip_atomic_load(src, __ATOMIC_RELAXED, __HIP_MEMORY_SCOPE_AGENT);
      while ((unsigned)u == 0xFFFFFFFFu || (unsigned)(u >> 32) == 0xFFFFFFFFu) {
        u = u2;
        u2 = __hip_atomic_load(src, __ATOMIC_RELAXED, __HIP_MEMORY_SCOPE_AGENT);
      }
      float hx = __builtin_bit_cast(float, (unsigned)u);
      float hy = __builtin_bit_cast(float, (unsigned)(u >> 32));
      hs_pk[w * 64 + l] =
          __builtin_bit_cast(unsigned, __builtin_amdgcn_cvt_pkrtz(hx, hy));
      asm volatile("s_waitcnt lgkmcnt(0)" ::: "memory");
      __builtin_amdgcn_sched_barrier(0);
      // dot: 16 x b128 LDS reads (wave-uniform broadcast) + 64 fdot2
      const uint4* hv = reinterpret_cast<const uint4*>(&hs_pk[w * 64]);
#pragma unroll
      for (int jj = 0; jj < 16; ++jj) {
        uint4 q = hv[jj];
        a0 = dot2(wpk[jj * 4 + 0], q.x, a0);
        a1 = dot2(wpk[jj * 4 + 1], q.y, a1);
        a2 = dot2(wpk[jj * 4 + 2], q.z, a2);
        a3 = dot2(wpk[jj * 4 + 3], q.w, a3);
      }
    }
    part_s[t & 1][w][l] = (a0 + a1) + (a2 + a3);
    __syncthreads();

    if (w == 0) {
      float sum = xp + part_s[t & 1][0][l] + part_s[t & 1][1][l] +
                  part_s[t & 1][2][l] + part_s[t & 1][3][l];
      float val = (g == 2) ? tanh_fast(sum) : sigm_fast(sum);
      float vf = __shfl(val, e + 16);   // f gate
      float vg = __shfl(val, e + 32);   // g gate
      float vo = __shfl(val, e + 48);   // o gate
      if (l < 16) {
        float c = vf * c_reg + val * vg;   // val = i for lanes 0..15
        c_reg = c;
        float h = vo * tanh_fast(c);
        long oidx = ((long)batch * 512 + t) * 512 + slice * 16 + l;
        __hip_atomic_store(reinterpret_cast<unsigned int*>(lstm_f32) + oidx,
                           __builtin_bit_cast(unsigned int, h),
                           __ATOMIC_RELAXED, __HIP_MEMORY_SCOPE_AGENT);
        lstm_hi[oidx] = f2bf(h);
      }
    }
    // no trailing barrier: part_s double-buffered; hs_pk segment wave-private
  }
}

// ---------- launch ----------
extern "C" void kernel_launch(void* const* d_in, const int* in_sizes, int n_in,
                              void* d_out, int out_size, void* d_ws, size_t ws_size,
                              hipStream_t stream) {
  const int*   x         = (const int*)d_in[0];
  const float* embedding = (const float*)d_in[2];
  const float* w_ih      = (const float*)d_in[3];
  const float* w_hh      = (const float*)d_in[4];
  const float* b_ih      = (const float*)d_in[5];
  const float* b_hh      = (const float*)d_in[6];
  const float* dec_w     = (const float*)d_in[7];
  const float* dec_b     = (const float*)d_in[8];

  char* ws = (char*)d_ws;
  float* xproj = (float*)ws;                      ws += (size_t)4096 * 2048 * 4;
  float* lstmf = (float*)ws;                      ws += (size_t)4096 * 512 * 4;
  unsigned short* lstm_hi = (unsigned short*)ws;  ws += (size_t)4096 * 512 * 2;
  unsigned short* emb_hi  = (unsigned short*)ws;  ws += (size_t)4096 * 512 * 2;
  unsigned short* emb_lo  = (unsigned short*)ws;  ws += (size_t)4096 * 512 * 2;
  unsigned short* wih_hi  = (unsigned short*)ws;  ws += (size_t)2048 * 512 * 2;
  unsigned short* wih_lo  = (unsigned short*)ws;  ws += (size_t)2048 * 512 * 2;
  unsigned short* dw_hi   = (unsigned short*)ws;  ws += (size_t)50000 * 512 * 2;

  // reset h sentinel (poll buffer) every call — determinism across replays
  hipMemsetAsync(lstmf, 0xFF, (size_t)4096 * 512 * 4, stream);

  split_hl<<<1024, 256, 0, stream>>>(w_ih, wih_hi, wih_lo, 2048 * 512 / 4);
  split_h<<<25000, 256, 0, stream>>>(dec_w, dw_hi, 50000 * 512 / 4);
  gather_split<<<2048, 256, 0, stream>>>(x, embedding, emb_hi, emb_lo);

  // xproj = embed @ w_ih^T + (b_ih + b_hh)   [3-product: feeds the recurrence]
  gemm_split<<<32 * 16, 256, 0, stream>>>(emb_hi, emb_lo, wih_hi, wih_lo, xproj,
                                          b_ih, b_hh, 2048, 32);

  {
    void* args[] = {(void*)&xproj, (void*)&w_hh, (void*)&lstmf, (void*)&lstm_hi};
    hipLaunchCooperativeKernel((void*)lstm_persistent, dim3(256), dim3(256), args, 0, stream);
  }

  // y = lstm_out @ dec_w^T + dec_b   [single bf16 product, 128^2 tile, 8x1 XCD map]
  gemm_plain<<<32 * 391, 256, 0, stream>>>(lstm_hi, dw_hi, (float*)d_out, dec_b, 50000);
}